// Round 7
// baseline (481.777 us; speedup 1.0000x reference)
//
#include <hip/hip_runtime.h>

// B=2, T=2048, C=1024, H=16, d=64. Inputs/outputs fp32; internal bf16 MFMA.
typedef unsigned short u16;
typedef u16   u16x4  __attribute__((ext_vector_type(4)));
typedef u16   u16x8  __attribute__((ext_vector_type(8)));
typedef __bf16 bf16x8 __attribute__((ext_vector_type(8)));
typedef float  f32x4  __attribute__((ext_vector_type(4)));

__device__ __forceinline__ float bf2f(u16 v) {
    unsigned u = ((unsigned)v) << 16;
    return __builtin_bit_cast(float, u);
}
__device__ __forceinline__ u16 f2bf(float f) {
    unsigned u = __builtin_bit_cast(unsigned, f);
    u += 0x7fffu + ((u >> 16) & 1u);   // RNE
    return (u16)(u >> 16);
}

// Packed operand images: per (bh, 64-s-chunk) a 512-slot x 8-elem tile (4096 u16).
// K-operand image (k=d): slot = (d>>3)*64 + (s&63), elem = d&7
__device__ __forceinline__ size_t kimg_idx(int bh, int s, int d) {
    return ((size_t)(bh * 32 + (s >> 6)) * 4096) + (size_t)(((d >> 3) * 64 + (s & 63)) * 8) + (d & 7);
}
// V-operand image (k=s): slot = ((s&63)>>3)*64 + d, elem = s&7
__device__ __forceinline__ size_t vimg_idx(int bh, int s, int d) {
    return ((size_t)(bh * 32 + (s >> 6)) * 4096) + (size_t)((((s & 63) >> 3) * 64 + d) * 8) + (s & 7);
}

// ---------------------------------------------------------------------------
// fp32 x -> bf16 row-major xb AND V-image xpack.
// ---------------------------------------------------------------------------
__global__ __launch_bounds__(256)
void convert_pack(const float* __restrict__ in, u16* __restrict__ xb,
                  u16* __restrict__ xpack) {
    int i = blockIdx.x * 256 + threadIdx.x;       // [0, 1048576)
    int c4 = i & 255, row = i >> 8;               // row = b*2048 + s
    int s = row & 2047, b = row >> 11;
    float4 v = ((const float4*)in)[i];
    u16x4 o;
    o.x = f2bf(v.x); o.y = f2bf(v.y); o.z = f2bf(v.z); o.w = f2bf(v.w);
    ((u16x4*)xb)[i] = o;
    int h = c4 >> 4, d0 = (c4 & 15) * 4;
    size_t base = vimg_idx(b * 16 + h, s, d0);
    xpack[base]      = o.x;
    xpack[base + 8]  = o.y;
    xpack[base + 16] = o.z;
    xpack[base + 24] = o.w;
}

// ---------------------------------------------------------------------------
// All three weight transposes in one launch. grid (64,16).
// bx<32: W_attn [1024x2048]; bx in [32,48): W_k2; bx>=48: W_proj.
// ---------------------------------------------------------------------------
__global__ __launch_bounds__(256)
void prep_weights(const float* __restrict__ Wa, const float* __restrict__ Wk,
                  const float* __restrict__ Wp, u16* __restrict__ Wta,
                  u16* __restrict__ Wtk, u16* __restrict__ Wtp) {
    __shared__ u16 tile[64][65];
    const int bx = blockIdx.x;
    const float* in; u16* out; int Cd, cx;
    if (bx < 32)      { in = Wa; out = Wta; Cd = 2048; cx = bx; }
    else if (bx < 48) { in = Wk; out = Wtk; Cd = 1024; cx = bx - 32; }
    else              { in = Wp; out = Wtp; Cd = 1024; cx = bx - 48; }
    const int c0 = cx * 64, r0 = blockIdx.y * 64;
    const int tid = threadIdx.x;
#pragma unroll
    for (int i = 0; i < 16; ++i) {
        int idx = tid + i * 256;
        int r = idx >> 6, c = idx & 63;
        tile[r][c] = f2bf(in[(size_t)(r0 + r) * Cd + c0 + c]);
    }
    __syncthreads();
#pragma unroll
    for (int i = 0; i < 16; ++i) {
        int idx = tid + i * 256;
        int r = idx >> 6, c = idx & 63;
        out[(size_t)(c0 + r) * 1024 + r0 + c] = tile[c][r];
    }
}

// ---------------------------------------------------------------------------
// qk GEMM: [4096 x 2048] = xb @ Wt_attn^T. 128x128 tile, prefetch-reordered.
// Epilogue: n<1024 -> qs row-major scaled 0.125; n>=1024 -> kpack K-image.
// ---------------------------------------------------------------------------
__global__ __launch_bounds__(256, 2)
void gemm_qk(const u16* __restrict__ A, const u16* __restrict__ Bt,
             u16* __restrict__ qs, u16* __restrict__ kpack, int K) {
    __shared__ __align__(16) u16 As[4][128][8];
    __shared__ __align__(16) u16 Bs[4][128][8];
    const int tid = threadIdx.x;
    const int wave = tid >> 6, lane = tid & 63;
    const int m0 = blockIdx.y * 128, n0 = blockIdx.x * 128;
    const int wm = (wave >> 1) * 64, wn = (wave & 1) * 64;
    const int q = lane >> 4, mr = lane & 15;
    const int sr = tid >> 2, c8 = tid & 3;
    const u16* Ap = A + (size_t)(m0 + sr) * K + c8 * 8;
    const u16* Bp = Bt + (size_t)(n0 + sr) * K + c8 * 8;

    f32x4 acc[4][4];
#pragma unroll
    for (int i = 0; i < 4; ++i)
#pragma unroll
        for (int j = 0; j < 4; ++j) acc[i][j] = f32x4{0.f, 0.f, 0.f, 0.f};

    u16x8 a0, a1, b0, b1;
    auto gload = [&](int k0) {
        a0 = *(const u16x8*)(Ap + k0);
        a1 = *(const u16x8*)(Ap + k0 + (size_t)64 * K);
        b0 = *(const u16x8*)(Bp + k0);
        b1 = *(const u16x8*)(Bp + k0 + (size_t)64 * K);
    };
    gload(0);
    for (int k0 = 0; k0 < K; k0 += 32) {
        __syncthreads();
        *(u16x8*)&As[c8][sr][0]      = a0;
        *(u16x8*)&As[c8][sr + 64][0] = a1;
        *(u16x8*)&Bs[c8][sr][0]      = b0;
        *(u16x8*)&Bs[c8][sr + 64][0] = b1;
        __syncthreads();
        if (k0 + 32 < K) gload(k0 + 32);
        bf16x8 af[4], bfr[4];
#pragma unroll
        for (int i = 0; i < 4; ++i) af[i]  = *(const bf16x8*)&As[q][wm + i * 16 + mr][0];
#pragma unroll
        for (int j = 0; j < 4; ++j) bfr[j] = *(const bf16x8*)&Bs[q][wn + j * 16 + mr][0];
#pragma unroll
        for (int i = 0; i < 4; ++i)
#pragma unroll
            for (int j = 0; j < 4; ++j)
                acc[i][j] = __builtin_amdgcn_mfma_f32_16x16x32_bf16(af[i], bfr[j], acc[i][j], 0, 0, 0);
    }
#pragma unroll
    for (int i = 0; i < 4; ++i)
#pragma unroll
        for (int j = 0; j < 4; ++j)
#pragma unroll
            for (int r = 0; r < 4; ++r) {
                int m = m0 + wm + i * 16 + q * 4 + r;
                int n = n0 + wn + j * 16 + mr;
                float v = acc[i][j][r];
                if (n < 1024) {
                    qs[(size_t)m * 1024 + n] = f2bf(v * 0.125f);
                } else {
                    int b = m >> 11, s = m & 2047, nn = n - 1024;
                    kpack[kimg_idx(b * 16 + (nn >> 6), s, nn & 63)] = f2bf(v);
                }
            }
}

// ---------------------------------------------------------------------------
// 64x128-tile GEMM. EPI: 1 = fp32 row-major out, 2 = sigmoid into K-image.
// ---------------------------------------------------------------------------
template <int EPI>
__global__ __launch_bounds__(256, 2)
void gemm64(const u16* __restrict__ A, const u16* __restrict__ Bt,
            void* __restrict__ Cv, int N, int K) {
    __shared__ __align__(16) u16 As[4][64][8];
    __shared__ __align__(16) u16 Bs[4][128][8];
    const int tid = threadIdx.x;
    const int wave = tid >> 6, lane = tid & 63;
    const int m0 = blockIdx.y * 64, n0 = blockIdx.x * 128;
    const int wn0 = wave * 32;
    const int q = lane >> 4, mr = lane & 15;
    const int sr = tid >> 2, c8 = tid & 3;
    const u16* Ap = A + (size_t)(m0 + sr) * K + c8 * 8;
    const u16* Bp = Bt + (size_t)(n0 + sr) * K + c8 * 8;

    f32x4 acc[4][2];
#pragma unroll
    for (int i = 0; i < 4; ++i)
#pragma unroll
        for (int j = 0; j < 2; ++j) acc[i][j] = f32x4{0.f, 0.f, 0.f, 0.f};

    u16x8 a0, b0, b1;
    auto gload = [&](int k0) {
        a0 = *(const u16x8*)(Ap + k0);
        b0 = *(const u16x8*)(Bp + k0);
        b1 = *(const u16x8*)(Bp + k0 + (size_t)64 * K);
    };
    gload(0);
    for (int k0 = 0; k0 < K; k0 += 32) {
        __syncthreads();
        *(u16x8*)&As[c8][sr][0]      = a0;
        *(u16x8*)&Bs[c8][sr][0]      = b0;
        *(u16x8*)&Bs[c8][sr + 64][0] = b1;
        __syncthreads();
        if (k0 + 32 < K) gload(k0 + 32);
        bf16x8 af[4], bfr[2];
#pragma unroll
        for (int i = 0; i < 4; ++i) af[i]  = *(const bf16x8*)&As[q][i * 16 + mr][0];
#pragma unroll
        for (int j = 0; j < 2; ++j) bfr[j] = *(const bf16x8*)&Bs[q][wn0 + j * 16 + mr][0];
#pragma unroll
        for (int i = 0; i < 4; ++i)
#pragma unroll
            for (int j = 0; j < 2; ++j)
                acc[i][j] = __builtin_amdgcn_mfma_f32_16x16x32_bf16(af[i], bfr[j], acc[i][j], 0, 0, 0);
    }
#pragma unroll
    for (int i = 0; i < 4; ++i)
#pragma unroll
        for (int j = 0; j < 2; ++j)
#pragma unroll
            for (int r = 0; r < 4; ++r) {
                int m = m0 + i * 16 + q * 4 + r;
                int n = n0 + wn0 + j * 16 + mr;
                float v = acc[i][j][r];
                if (EPI == 1) {
                    ((float*)Cv)[(size_t)m * N + n] = v;
                } else {
                    int b = m >> 11, s = m & 2047;
                    ((u16*)Cv)[kimg_idx(b * 16 + (n >> 6), s, n & 63)] =
                        f2bf(1.f / (1.f + __expf(-0.0025f * v)));
                }
            }
}

// ---------------------------------------------------------------------------
// Flash attention: 128-row t-tiles (2 m-tiles/wave: {w, w+4}), s-split (z =
// chunk parity), fixed-shift-free softmax partials. Block bx handles tile
// pair {bx, 15-bx}. LDS/work halved vs 64-row version (K/V frags cached
// in regs across both m-tiles).
// ---------------------------------------------------------------------------
__global__ __launch_bounds__(256, 2)
void flash_mfma(const u16* __restrict__ qs, const u16* __restrict__ kpack,
                const u16* __restrict__ xpack, u16* __restrict__ Opart,
                float* __restrict__ lpart) {
    __shared__ __align__(16) u16 Ks[8][64][8];
    __shared__ __align__(16) u16 Vs[8][64][8];
    __shared__ __align__(16) u16 Ps[4][16][72];
    const int bh = blockIdx.y, b = bh >> 4, hc = (bh & 15) * 64;
    const int z = blockIdx.z;
    const int tid = threadIdx.x, w = tid >> 6, lane = tid & 63;
    const int n16 = lane & 15, quad = lane >> 4;
    const u16* kbase = kpack + (size_t)bh * 32 * 4096;
    const u16* vbase = xpack + (size_t)bh * 32 * 4096;
    u16* Ob = Opart + (size_t)z * 4096 * 1024;
    float* lb = lpart + z * 65536;

    for (int rep = 0; rep < 2; ++rep) {
        const int T = rep ? 15 - (int)blockIdx.x : (int)blockIdx.x;
        const int t0 = T * 128;
        const int nchunk = 2 * T + 2;

        bf16x8 qf[2][2];
#pragma unroll
        for (int mt = 0; mt < 2; ++mt) {
            const int trow = t0 + (w + mt * 4) * 16 + n16;
            const u16* qp = &qs[(size_t)(b * 2048 + trow) * 1024 + hc + quad * 8];
            qf[mt][0] = *(const bf16x8*)qp;
            qf[mt][1] = *(const bf16x8*)(qp + 32);
        }

        f32x4 O[2][4];
        float lsum[2][4];
#pragma unroll
        for (int mt = 0; mt < 2; ++mt)
#pragma unroll
            for (int jt = 0; jt < 4; ++jt) { O[mt][jt] = f32x4{0.f, 0.f, 0.f, 0.f}; }
#pragma unroll
        for (int mt = 0; mt < 2; ++mt)
#pragma unroll
            for (int r = 0; r < 4; ++r) lsum[mt][r] = 0.f;

        u16x8 kr0, kr1, vr0, vr1;
        auto pref = [&](int c) {
            const u16* kc = kbase + (size_t)c * 4096;
            const u16* vc = vbase + (size_t)c * 4096;
            kr0 = *(const u16x8*)(kc + tid * 8);
            kr1 = *(const u16x8*)(kc + (256 + tid) * 8);
            vr0 = *(const u16x8*)(vc + tid * 8);
            vr1 = *(const u16x8*)(vc + (256 + tid) * 8);
        };
        if (z < nchunk) pref(z);

        for (int c = z; c < nchunk; c += 2) {
            __syncthreads();
            *(u16x8*)((u16*)Ks + tid * 8)         = kr0;
            *(u16x8*)((u16*)Ks + (256 + tid) * 8) = kr1;
            *(u16x8*)((u16*)Vs + tid * 8)         = vr0;
            *(u16x8*)((u16*)Vs + (256 + tid) * 8) = vr1;
            __syncthreads();
            if (c + 2 < nchunk) pref(c + 2);

            // S = Q K^T for both m-tiles; K frags read once, reused.
            f32x4 S[2][4];
#pragma unroll
            for (int mt = 0; mt < 2; ++mt)
#pragma unroll
                for (int jt = 0; jt < 4; ++jt) S[mt][jt] = f32x4{0.f, 0.f, 0.f, 0.f};
#pragma unroll
            for (int ks = 0; ks < 2; ++ks)
#pragma unroll
                for (int jt = 0; jt < 4; ++jt) {
                    bf16x8 kf = *(const bf16x8*)&Ks[ks * 4 + quad][jt * 16 + n16][0];
                    S[0][jt] = __builtin_amdgcn_mfma_f32_16x16x32_bf16(qf[0][ks], kf, S[0][jt], 0, 0, 0);
                    S[1][jt] = __builtin_amdgcn_mfma_f32_16x16x32_bf16(qf[1][ks], kf, S[1][jt], 0, 0, 0);
                }
            // V frags cached for both m-tiles.
            bf16x8 vf[2][4];
#pragma unroll
            for (int ks = 0; ks < 2; ++ks)
#pragma unroll
                for (int jt = 0; jt < 4; ++jt)
                    vf[ks][jt] = *(const bf16x8*)&Vs[ks * 4 + quad][jt * 16 + n16][0];

            const int mt0 = (c == 2 * T + 1) ? 1 : 0;   // lower half fully masked
            for (int mt = mt0; mt < 2; ++mt) {
                float p[4][4];
#pragma unroll
                for (int reg = 0; reg < 4; ++reg)
#pragma unroll
                    for (int jt = 0; jt < 4; ++jt)
                        p[reg][jt] = __expf(S[mt][jt][reg]);
                if (c == 2 * T + mt) {   // partially-masked diagonal subtile
#pragma unroll
                    for (int reg = 0; reg < 4; ++reg) {
                        const int tr = t0 + (w + mt * 4) * 16 + quad * 4 + reg;
#pragma unroll
                        for (int jt = 0; jt < 4; ++jt)
                            if (c * 64 + jt * 16 + n16 > tr) p[reg][jt] = 0.f;
                    }
                }
#pragma unroll
                for (int reg = 0; reg < 4; ++reg) {
                    lsum[mt][reg] += (p[reg][0] + p[reg][1]) + (p[reg][2] + p[reg][3]);
#pragma unroll
                    for (int jt = 0; jt < 4; ++jt)
                        Ps[w][quad * 4 + reg][jt * 16 + n16] = f2bf(p[reg][jt]);
                }
                bf16x8 pf[2];
#pragma unroll
                for (int ks = 0; ks < 2; ++ks)
                    pf[ks] = *(const bf16x8*)&Ps[w][n16][ks * 32 + quad * 8];
#pragma unroll
                for (int ks = 0; ks < 2; ++ks)
#pragma unroll
                    for (int jt = 0; jt < 4; ++jt)
                        O[mt][jt] = __builtin_amdgcn_mfma_f32_16x16x32_bf16(pf[ks], vf[ks][jt], O[mt][jt], 0, 0, 0);
            }
        }

#pragma unroll
        for (int mt = 0; mt < 2; ++mt)
#pragma unroll
            for (int reg = 0; reg < 4; ++reg) {
                float l = lsum[mt][reg];
#pragma unroll
                for (int off = 1; off < 16; off <<= 1) l += __shfl_xor(l, off, 64);
                const int tr = t0 + (w + mt * 4) * 16 + quad * 4 + reg;
                if (n16 == 0) lb[bh * 2048 + tr] = l;
                const size_t row = (size_t)(b * 2048 + tr) * 1024 + hc;
#pragma unroll
                for (int jt = 0; jt < 4; ++jt)
                    Ob[row + jt * 16 + n16] = f2bf(O[mt][jt][reg]);
            }
    }
}

// ---------------------------------------------------------------------------
// combine flash halves: y = (O0+O1)/(l0+l1); epack = V-image of x[t+1]-y[t].
// ---------------------------------------------------------------------------
__global__ __launch_bounds__(256)
void combine_flash(const u16* __restrict__ Opart, const float* __restrict__ lpart,
                   const u16* __restrict__ xb, u16* __restrict__ y,
                   u16* __restrict__ epack) {
    int i = blockIdx.x * 256 + threadIdx.x;
    int c4 = i & 255, row = i >> 8, t = row & 2047, b = row >> 11;
    int h = c4 >> 4, d0 = (c4 & 15) * 4;
    size_t off = (size_t)row * 1024 + c4 * 4;
    u16x4 o0 = *(const u16x4*)&Opart[off];
    u16x4 o1 = *(const u16x4*)&Opart[(size_t)4096 * 1024 + off];
    int lrow = (b * 16 + h) * 2048 + t;
    float inv = 1.f / (lpart[lrow] + lpart[65536 + lrow]);
    float y0 = (bf2f(o0.x) + bf2f(o1.x)) * inv;
    float y1 = (bf2f(o0.y) + bf2f(o1.y)) * inv;
    float y2 = (bf2f(o0.z) + bf2f(o1.z)) * inv;
    float y3 = (bf2f(o0.w) + bf2f(o1.w)) * inv;
    u16x4 yo;
    yo.x = f2bf(y0); yo.y = f2bf(y1); yo.z = f2bf(y2); yo.w = f2bf(y3);
    *(u16x4*)&y[off] = yo;
    float e0 = 0.f, e1 = 0.f, e2 = 0.f, e3 = 0.f;
    if (t < 2047) {
        u16x4 xv = *(const u16x4*)&xb[off + 1024];
        e0 = bf2f(xv.x) - y0; e1 = bf2f(xv.y) - y1;
        e2 = bf2f(xv.z) - y2; e3 = bf2f(xv.w) - y3;
    }
    size_t base = vimg_idx(b * 16 + h, t, d0);
    epack[base]      = f2bf(e0);
    epack[base + 8]  = f2bf(e1);
    epack[base + 16] = f2bf(e2);
    epack[base + 24] = f2bf(e3);
}

// ---------------------------------------------------------------------------
// ARMA, same 128-row structure, strict mask, no softmax.
// ---------------------------------------------------------------------------
__global__ __launch_bounds__(256, 2)
void arma_mfma(const u16* __restrict__ qs, const u16* __restrict__ kapack,
               const u16* __restrict__ epack, u16* __restrict__ Opart) {
    __shared__ __align__(16) u16 Ks[8][64][8];
    __shared__ __align__(16) u16 Es[8][64][8];
    __shared__ __align__(16) u16 Ps[4][16][72];
    const int bh = blockIdx.y, b = bh >> 4, hc = (bh & 15) * 64;
    const int z = blockIdx.z;
    const int tid = threadIdx.x, w = tid >> 6, lane = tid & 63;
    const int n16 = lane & 15, quad = lane >> 4;
    const u16* kbase = kapack + (size_t)bh * 32 * 4096;
    const u16* vbase = epack + (size_t)bh * 32 * 4096;
    u16* Ob = Opart + (size_t)z * 4096 * 1024;

    for (int rep = 0; rep < 2; ++rep) {
        const int T = rep ? 15 - (int)blockIdx.x : (int)blockIdx.x;
        const int t0 = T * 128;
        const int nchunk = 2 * T + 2;

        bf16x8 qf[2][2];
#pragma unroll
        for (int mt = 0; mt < 2; ++mt) {
            const int trow = t0 + (w + mt * 4) * 16 + n16;
            const u16* qp = &qs[(size_t)(b * 2048 + trow) * 1024 + hc + quad * 8];
#pragma unroll
            for (int ks = 0; ks < 2; ++ks) {
                u16x8 qv = *(const u16x8*)(qp + ks * 32);
                u16x8 o;
#pragma unroll
                for (int j = 0; j < 8; ++j) {
                    float zv = bf2f(qv[j]);              // pre-scaled by 1/8
                    o[j] = f2bf(zv < 0.f ? zv : 0.02f * zv);
                }
                qf[mt][ks] = __builtin_bit_cast(bf16x8, o);
            }
        }

        f32x4 O[2][4];
#pragma unroll
        for (int mt = 0; mt < 2; ++mt)
#pragma unroll
            for (int jt = 0; jt < 4; ++jt) O[mt][jt] = f32x4{0.f, 0.f, 0.f, 0.f};

        u16x8 kr0, kr1, vr0, vr1;
        auto pref = [&](int c) {
            const u16* kc = kbase + (size_t)c * 4096;
            const u16* vc = vbase + (size_t)c * 4096;
            kr0 = *(const u16x8*)(kc + tid * 8);
            kr1 = *(const u16x8*)(kc + (256 + tid) * 8);
            vr0 = *(const u16x8*)(vc + tid * 8);
            vr1 = *(const u16x8*)(vc + (256 + tid) * 8);
        };
        if (z < nchunk) pref(z);

        for (int c = z; c < nchunk; c += 2) {
            __syncthreads();
            *(u16x8*)((u16*)Ks + tid * 8)         = kr0;
            *(u16x8*)((u16*)Ks + (256 + tid) * 8) = kr1;
            *(u16x8*)((u16*)Es + tid * 8)         = vr0;
            *(u16x8*)((u16*)Es + (256 + tid) * 8) = vr1;
            __syncthreads();
            if (c + 2 < nchunk) pref(c + 2);

            f32x4 S[2][4];
#pragma unroll
            for (int mt = 0; mt < 2; ++mt)
#pragma unroll
                for (int jt = 0; jt < 4; ++jt) S[mt][jt] = f32x4{0.f, 0.f, 0.f, 0.f};
#pragma unroll
            for (int ks = 0; ks < 2; ++ks)
#pragma unroll
                for (int jt = 0; jt < 4; ++jt) {
                    bf16x8 kf = *(const bf16x8*)&Ks[ks * 4 + quad][jt * 16 + n16][0];
                    S[0][jt] = __builtin_amdgcn_mfma_f32_16x16x32_bf16(qf[0][ks], kf, S[0][jt], 0, 0, 0);
                    S[1][jt] = __builtin_amdgcn_mfma_f32_16x16x32_bf16(qf[1][ks], kf, S[1][jt], 0, 0, 0);
                }
            bf16x8 vf[2][4];
#pragma unroll
            for (int ks = 0; ks < 2; ++ks)
#pragma unroll
                for (int jt = 0; jt < 4; ++jt)
                    vf[ks][jt] = *(const bf16x8*)&Es[ks * 4 + quad][jt * 16 + n16][0];

            const int mt0 = (c == 2 * T + 1) ? 1 : 0;
            for (int mt = mt0; mt < 2; ++mt) {
                if (c == 2 * T + mt) {   // strict mask s < t on diagonal subtile
#pragma unroll
                    for (int reg = 0; reg < 4; ++reg) {
                        const int tr = t0 + (w + mt * 4) * 16 + quad * 4 + reg;
#pragma unroll
                        for (int jt = 0; jt < 4; ++jt)
                            if (c * 64 + jt * 16 + n16 >= tr) S[mt][jt][reg] = 0.f;
                    }
                }
#pragma unroll
                for (int reg = 0; reg < 4; ++reg)
#pragma unroll
                    for (int jt = 0; jt < 4; ++jt)
                        Ps[w][quad * 4 + reg][jt * 16 + n16] = f2bf(S[mt][jt][reg]);
                bf16x8 pf[2];
#pragma unroll
                for (int ks = 0; ks < 2; ++ks)
                    pf[ks] = *(const bf16x8*)&Ps[w][n16][ks * 32 + quad * 8];
#pragma unroll
                for (int ks = 0; ks < 2; ++ks)
#pragma unroll
                    for (int jt = 0; jt < 4; ++jt)
                        O[mt][jt] = __builtin_amdgcn_mfma_f32_16x16x32_bf16(pf[ks], vf[ks][jt], O[mt][jt], 0, 0, 0);
            }
        }

#pragma unroll
        for (int mt = 0; mt < 2; ++mt)
#pragma unroll
            for (int reg = 0; reg < 4; ++reg) {
                const int tr = t0 + (w + mt * 4) * 16 + quad * 4 + reg;
                const size_t row = (size_t)(b * 2048 + tr) * 1024 + hc;
#pragma unroll
                for (int jt = 0; jt < 4; ++jt)
                    Ob[row + jt * 16 + n16] = f2bf(O[mt][jt][reg]);
            }
    }
}

// ---------------------------------------------------------------------------
// combine arma halves: ys = y + O0 + O1 (bf16).
// ---------------------------------------------------------------------------
__global__ __launch_bounds__(256)
void combine_arma(const u16* __restrict__ Opart, const u16* __restrict__ y,
                  u16* __restrict__ ys) {
    int i = blockIdx.x * 256 + threadIdx.x;
    size_t off = (size_t)i * 4;
    u16x4 o0 = *(const u16x4*)&Opart[off];
    u16x4 o1 = *(const u16x4*)&Opart[(size_t)4096 * 1024 + off];
    u16x4 yv = *(const u16x4*)&y[off];
    u16x4 r;
    r.x = f2bf(bf2f(yv.x) + bf2f(o0.x) + bf2f(o1.x));
    r.y = f2bf(bf2f(yv.y) + bf2f(o0.y) + bf2f(o1.y));
    r.z = f2bf(bf2f(yv.z) + bf2f(o0.z) + bf2f(o1.z));
    r.w = f2bf(bf2f(yv.w) + bf2f(o0.w) + bf2f(o1.w));
    *(u16x4*)&ys[off] = r;
}

// ---------------------------------------------------------------------------
extern "C" void kernel_launch(void* const* d_in, const int* in_sizes, int n_in,
                              void* d_out, int out_size, void* d_ws, size_t ws_size,
                              hipStream_t stream) {
    const float* x      = (const float*)d_in[0];
    const float* W_attn = (const float*)d_in[1];
    const float* W_k2   = (const float*)d_in[2];
    const float* W_proj = (const float*)d_in[3];
    float* out = (float*)d_out;

    char* w = (char*)d_ws;
    u16* xb      = (u16*)w; w += (size_t)4096 * 1024 * 2;   //  8 MB (reused as ys)
    u16* Wt_attn = (u16*)w; w += (size_t)2048 * 1024 * 2;   //  4 MB
    u16* Wt_k2   = (u16*)w; w += (size_t)1024 * 1024 * 2;   //  2 MB
    u16* Wt_proj = (u16*)w; w += (size_t)1024 * 1024 * 2;   //  2 MB
    u16* qs      = (u16*)w; w += (size_t)4096 * 1024 * 2;   //  8 MB
    u16* kpack   = (u16*)w; w += (size_t)4096 * 1024 * 2;   //  8 MB
    u16* kapack  = (u16*)w; w += (size_t)4096 * 1024 * 2;   //  8 MB
    u16* xpack   = (u16*)w; w += (size_t)4096 * 1024 * 2;   //  8 MB
    u16* y       = (u16*)w; w += (size_t)4096 * 1024 * 2;   //  8 MB
    u16* epack   = (u16*)w; w += (size_t)4096 * 1024 * 2;   //  8 MB
    u16* Opart   = (u16*)w; w += (size_t)2 * 4096 * 1024 * 2; // 16 MB
    float* lpart = (float*)w; w += (size_t)2 * 65536 * 4;   // 0.5 MB (~80.5 MB)
    u16* ys = xb;   // xb dead after combine_flash

    convert_pack<<<dim3(4096), dim3(256), 0, stream>>>(x, xb, xpack);
    prep_weights<<<dim3(64, 16), dim3(256), 0, stream>>>(W_attn, W_k2, W_proj,
                                                         Wt_attn, Wt_k2, Wt_proj);
    gemm_qk<<<dim3(16, 32), dim3(256), 0, stream>>>(xb, Wt_attn, qs, kpack, 1024);
    gemm64<2><<<dim3(8, 64), dim3(256), 0, stream>>>(xb, Wt_k2, kapack, 1024, 1024);
    flash_mfma<<<dim3(8, 32, 2), dim3(256), 0, stream>>>(qs, kpack, xpack, Opart, lpart);
    combine_flash<<<dim3(4096), dim3(256), 0, stream>>>(Opart, lpart, xb, y, epack);
    arma_mfma<<<dim3(8, 32, 2), dim3(256), 0, stream>>>(qs, kapack, epack, Opart);
    combine_arma<<<dim3(4096), dim3(256), 0, stream>>>(Opart, y, ys);
    gemm64<1><<<dim3(8, 64), dim3(256), 0, stream>>>(ys, Wt_proj, out, 1024, 1024);
}

// Round 8
// 281.860 us; speedup vs baseline: 1.7093x; 1.7093x over previous
//
#include <hip/hip_runtime.h>

// B=2, T=2048, C=1024, H=16, d=64. Inputs/outputs fp32; internal bf16 MFMA.
typedef unsigned short u16;
typedef u16   u16x4  __attribute__((ext_vector_type(4)));
typedef u16   u16x8  __attribute__((ext_vector_type(8)));
typedef __bf16 bf16x8 __attribute__((ext_vector_type(8)));
typedef float  f32x4  __attribute__((ext_vector_type(4)));

__device__ __forceinline__ float bf2f(u16 v) {
    unsigned u = ((unsigned)v) << 16;
    return __builtin_bit_cast(float, u);
}
__device__ __forceinline__ u16 f2bf(float f) {
    unsigned u = __builtin_bit_cast(unsigned, f);
    u += 0x7fffu + ((u >> 16) & 1u);   // RNE
    return (u16)(u >> 16);
}

// Packed operand images: per (bh, 64-s-chunk) a 512-slot x 8-elem tile (4096 u16).
// K-operand image (k=d): slot = (d>>3)*64 + (s&63), elem = d&7
__device__ __forceinline__ size_t kimg_idx(int bh, int s, int d) {
    return ((size_t)(bh * 32 + (s >> 6)) * 4096) + (size_t)(((d >> 3) * 64 + (s & 63)) * 8) + (d & 7);
}
// V-operand image (k=s): slot = ((s&63)>>3)*64 + d, elem = s&7
__device__ __forceinline__ size_t vimg_idx(int bh, int s, int d) {
    return ((size_t)(bh * 32 + (s >> 6)) * 4096) + (size_t)((((s & 63) >> 3) * 64 + d) * 8) + (s & 7);
}

// ---------------------------------------------------------------------------
// fp32 x -> bf16 row-major xb AND V-image xpack.
// ---------------------------------------------------------------------------
__global__ __launch_bounds__(256)
void convert_pack(const float* __restrict__ in, u16* __restrict__ xb,
                  u16* __restrict__ xpack) {
    int i = blockIdx.x * 256 + threadIdx.x;       // [0, 1048576)
    int c4 = i & 255, row = i >> 8;               // row = b*2048 + s
    int s = row & 2047, b = row >> 11;
    float4 v = ((const float4*)in)[i];
    u16x4 o;
    o.x = f2bf(v.x); o.y = f2bf(v.y); o.z = f2bf(v.z); o.w = f2bf(v.w);
    ((u16x4*)xb)[i] = o;
    int h = c4 >> 4, d0 = (c4 & 15) * 4;
    size_t base = vimg_idx(b * 16 + h, s, d0);
    xpack[base]      = o.x;
    xpack[base + 8]  = o.y;
    xpack[base + 16] = o.z;
    xpack[base + 24] = o.w;
}

// ---------------------------------------------------------------------------
// All three weight transposes in one launch. grid (64,16).
// ---------------------------------------------------------------------------
__global__ __launch_bounds__(256)
void prep_weights(const float* __restrict__ Wa, const float* __restrict__ Wk,
                  const float* __restrict__ Wp, u16* __restrict__ Wta,
                  u16* __restrict__ Wtk, u16* __restrict__ Wtp) {
    __shared__ u16 tile[64][65];
    const int bx = blockIdx.x;
    const float* in; u16* out; int Cd, cx;
    if (bx < 32)      { in = Wa; out = Wta; Cd = 2048; cx = bx; }
    else if (bx < 48) { in = Wk; out = Wtk; Cd = 1024; cx = bx - 32; }
    else              { in = Wp; out = Wtp; Cd = 1024; cx = bx - 48; }
    const int c0 = cx * 64, r0 = blockIdx.y * 64;
    const int tid = threadIdx.x;
#pragma unroll
    for (int i = 0; i < 16; ++i) {
        int idx = tid + i * 256;
        int r = idx >> 6, c = idx & 63;
        tile[r][c] = f2bf(in[(size_t)(r0 + r) * Cd + c0 + c]);
    }
    __syncthreads();
#pragma unroll
    for (int i = 0; i < 16; ++i) {
        int idx = tid + i * 256;
        int r = idx >> 6, c = idx & 63;
        out[(size_t)(c0 + r) * 1024 + r0 + c] = tile[c][r];
    }
}

// ---------------------------------------------------------------------------
// qk GEMM: [4096 x 2048] = xb @ Wt_attn^T. 128x128 tile, prefetch-reordered.
// Epilogue: n<1024 -> qs row-major scaled 0.125; n>=1024 -> kpack K-image.
// ---------------------------------------------------------------------------
__global__ __launch_bounds__(256, 2)
void gemm_qk(const u16* __restrict__ A, const u16* __restrict__ Bt,
             u16* __restrict__ qs, u16* __restrict__ kpack, int K) {
    __shared__ __align__(16) u16 As[4][128][8];
    __shared__ __align__(16) u16 Bs[4][128][8];
    const int tid = threadIdx.x;
    const int wave = tid >> 6, lane = tid & 63;
    const int m0 = blockIdx.y * 128, n0 = blockIdx.x * 128;
    const int wm = (wave >> 1) * 64, wn = (wave & 1) * 64;
    const int q = lane >> 4, mr = lane & 15;
    const int sr = tid >> 2, c8 = tid & 3;
    const u16* Ap = A + (size_t)(m0 + sr) * K + c8 * 8;
    const u16* Bp = Bt + (size_t)(n0 + sr) * K + c8 * 8;

    f32x4 acc[4][4];
#pragma unroll
    for (int i = 0; i < 4; ++i)
#pragma unroll
        for (int j = 0; j < 4; ++j) acc[i][j] = f32x4{0.f, 0.f, 0.f, 0.f};

    u16x8 a0, a1, b0, b1;
    auto gload = [&](int k0) {
        a0 = *(const u16x8*)(Ap + k0);
        a1 = *(const u16x8*)(Ap + k0 + (size_t)64 * K);
        b0 = *(const u16x8*)(Bp + k0);
        b1 = *(const u16x8*)(Bp + k0 + (size_t)64 * K);
    };
    gload(0);
    for (int k0 = 0; k0 < K; k0 += 32) {
        __syncthreads();
        *(u16x8*)&As[c8][sr][0]      = a0;
        *(u16x8*)&As[c8][sr + 64][0] = a1;
        *(u16x8*)&Bs[c8][sr][0]      = b0;
        *(u16x8*)&Bs[c8][sr + 64][0] = b1;
        __syncthreads();
        if (k0 + 32 < K) gload(k0 + 32);
        bf16x8 af[4], bfr[4];
#pragma unroll
        for (int i = 0; i < 4; ++i) af[i]  = *(const bf16x8*)&As[q][wm + i * 16 + mr][0];
#pragma unroll
        for (int j = 0; j < 4; ++j) bfr[j] = *(const bf16x8*)&Bs[q][wn + j * 16 + mr][0];
#pragma unroll
        for (int i = 0; i < 4; ++i)
#pragma unroll
            for (int j = 0; j < 4; ++j)
                acc[i][j] = __builtin_amdgcn_mfma_f32_16x16x32_bf16(af[i], bfr[j], acc[i][j], 0, 0, 0);
    }
#pragma unroll
    for (int i = 0; i < 4; ++i)
#pragma unroll
        for (int j = 0; j < 4; ++j)
#pragma unroll
            for (int r = 0; r < 4; ++r) {
                int m = m0 + wm + i * 16 + q * 4 + r;
                int n = n0 + wn + j * 16 + mr;
                float v = acc[i][j][r];
                if (n < 1024) {
                    qs[(size_t)m * 1024 + n] = f2bf(v * 0.125f);
                } else {
                    int b = m >> 11, s = m & 2047, nn = n - 1024;
                    kpack[kimg_idx(b * 16 + (nn >> 6), s, nn & 63)] = f2bf(v);
                }
            }
}

// ---------------------------------------------------------------------------
// 64x128-tile GEMM. EPI: 1 = fp32 row-major out, 2 = sigmoid into K-image.
// ---------------------------------------------------------------------------
template <int EPI>
__global__ __launch_bounds__(256, 2)
void gemm64(const u16* __restrict__ A, const u16* __restrict__ Bt,
            void* __restrict__ Cv, int N, int K) {
    __shared__ __align__(16) u16 As[4][64][8];
    __shared__ __align__(16) u16 Bs[4][128][8];
    const int tid = threadIdx.x;
    const int wave = tid >> 6, lane = tid & 63;
    const int m0 = blockIdx.y * 64, n0 = blockIdx.x * 128;
    const int wn0 = wave * 32;
    const int q = lane >> 4, mr = lane & 15;
    const int sr = tid >> 2, c8 = tid & 3;
    const u16* Ap = A + (size_t)(m0 + sr) * K + c8 * 8;
    const u16* Bp = Bt + (size_t)(n0 + sr) * K + c8 * 8;

    f32x4 acc[4][2];
#pragma unroll
    for (int i = 0; i < 4; ++i)
#pragma unroll
        for (int j = 0; j < 2; ++j) acc[i][j] = f32x4{0.f, 0.f, 0.f, 0.f};

    u16x8 a0, b0, b1;
    auto gload = [&](int k0) {
        a0 = *(const u16x8*)(Ap + k0);
        b0 = *(const u16x8*)(Bp + k0);
        b1 = *(const u16x8*)(Bp + k0 + (size_t)64 * K);
    };
    gload(0);
    for (int k0 = 0; k0 < K; k0 += 32) {
        __syncthreads();
        *(u16x8*)&As[c8][sr][0]      = a0;
        *(u16x8*)&Bs[c8][sr][0]      = b0;
        *(u16x8*)&Bs[c8][sr + 64][0] = b1;
        __syncthreads();
        if (k0 + 32 < K) gload(k0 + 32);
        bf16x8 af[4], bfr[2];
#pragma unroll
        for (int i = 0; i < 4; ++i) af[i]  = *(const bf16x8*)&As[q][i * 16 + mr][0];
#pragma unroll
        for (int j = 0; j < 2; ++j) bfr[j] = *(const bf16x8*)&Bs[q][wn0 + j * 16 + mr][0];
#pragma unroll
        for (int i = 0; i < 4; ++i)
#pragma unroll
            for (int j = 0; j < 2; ++j)
                acc[i][j] = __builtin_amdgcn_mfma_f32_16x16x32_bf16(af[i], bfr[j], acc[i][j], 0, 0, 0);
    }
#pragma unroll
    for (int i = 0; i < 4; ++i)
#pragma unroll
        for (int j = 0; j < 2; ++j)
#pragma unroll
            for (int r = 0; r < 4; ++r) {
                int m = m0 + i * 16 + q * 4 + r;
                int n = n0 + wn0 + j * 16 + mr;
                float v = acc[i][j][r];
                if (EPI == 1) {
                    ((float*)Cv)[(size_t)m * N + n] = v;
                } else {
                    int b = m >> 11, s = m & 2047;
                    ((u16*)Cv)[kimg_idx(b * 16 + (n >> 6), s, n & 63)] =
                        f2bf(1.f / (1.f + __expf(-0.0025f * v)));
                }
            }
}

// ---------------------------------------------------------------------------
// Flash attention: 128-row t-tiles (2 m-tiles/wave: {w, w+4}), s-split (z =
// chunk parity). Block bx handles tile pair {bx, 15-bx}. All register arrays
// indexed by compile-time constants (mt loop statically unrolled — dynamic
// lower bound caused scratch demotion in R7: WRITE_SIZE 571 MB).
// ---------------------------------------------------------------------------
__global__ __launch_bounds__(256, 2)
void flash_mfma(const u16* __restrict__ qs, const u16* __restrict__ kpack,
                const u16* __restrict__ xpack, u16* __restrict__ Opart,
                float* __restrict__ lpart) {
    __shared__ __align__(16) u16 Ks[8][64][8];
    __shared__ __align__(16) u16 Vs[8][64][8];
    __shared__ __align__(16) u16 Ps[4][16][72];
    const int bh = blockIdx.y, b = bh >> 4, hc = (bh & 15) * 64;
    const int z = blockIdx.z;
    const int tid = threadIdx.x, w = tid >> 6, lane = tid & 63;
    const int n16 = lane & 15, quad = lane >> 4;
    const u16* kbase = kpack + (size_t)bh * 32 * 4096;
    const u16* vbase = xpack + (size_t)bh * 32 * 4096;
    u16* Ob = Opart + (size_t)z * 4096 * 1024;
    float* lb = lpart + z * 65536;

    for (int rep = 0; rep < 2; ++rep) {
        const int T = rep ? 15 - (int)blockIdx.x : (int)blockIdx.x;
        const int t0 = T * 128;
        const int nchunk = 2 * T + 2;

        bf16x8 qf[2][2];
#pragma unroll
        for (int mt = 0; mt < 2; ++mt) {
            const int trow = t0 + (w + mt * 4) * 16 + n16;
            const u16* qp = &qs[(size_t)(b * 2048 + trow) * 1024 + hc + quad * 8];
            qf[mt][0] = *(const bf16x8*)qp;
            qf[mt][1] = *(const bf16x8*)(qp + 32);
        }

        f32x4 O[2][4];
        float lsum[2][4];
#pragma unroll
        for (int mt = 0; mt < 2; ++mt)
#pragma unroll
            for (int jt = 0; jt < 4; ++jt) { O[mt][jt] = f32x4{0.f, 0.f, 0.f, 0.f}; }
#pragma unroll
        for (int mt = 0; mt < 2; ++mt)
#pragma unroll
            for (int r = 0; r < 4; ++r) lsum[mt][r] = 0.f;

        u16x8 kr0, kr1, vr0, vr1;
        auto pref = [&](int c) {
            const u16* kc = kbase + (size_t)c * 4096;
            const u16* vc = vbase + (size_t)c * 4096;
            kr0 = *(const u16x8*)(kc + tid * 8);
            kr1 = *(const u16x8*)(kc + (256 + tid) * 8);
            vr0 = *(const u16x8*)(vc + tid * 8);
            vr1 = *(const u16x8*)(vc + (256 + tid) * 8);
        };
        if (z < nchunk) pref(z);

        for (int c = z; c < nchunk; c += 2) {
            __syncthreads();
            *(u16x8*)((u16*)Ks + tid * 8)         = kr0;
            *(u16x8*)((u16*)Ks + (256 + tid) * 8) = kr1;
            *(u16x8*)((u16*)Vs + tid * 8)         = vr0;
            *(u16x8*)((u16*)Vs + (256 + tid) * 8) = vr1;
            __syncthreads();
            if (c + 2 < nchunk) pref(c + 2);

            // S = Q K^T for both m-tiles; K frags read once, reused.
            f32x4 S[2][4];
#pragma unroll
            for (int mt = 0; mt < 2; ++mt)
#pragma unroll
                for (int jt = 0; jt < 4; ++jt) S[mt][jt] = f32x4{0.f, 0.f, 0.f, 0.f};
#pragma unroll
            for (int ks = 0; ks < 2; ++ks)
#pragma unroll
                for (int jt = 0; jt < 4; ++jt) {
                    bf16x8 kf = *(const bf16x8*)&Ks[ks * 4 + quad][jt * 16 + n16][0];
                    S[0][jt] = __builtin_amdgcn_mfma_f32_16x16x32_bf16(qf[0][ks], kf, S[0][jt], 0, 0, 0);
                    S[1][jt] = __builtin_amdgcn_mfma_f32_16x16x32_bf16(qf[1][ks], kf, S[1][jt], 0, 0, 0);
                }
            // V frags cached for both m-tiles.
            bf16x8 vf[2][4];
#pragma unroll
            for (int ks = 0; ks < 2; ++ks)
#pragma unroll
                for (int jt = 0; jt < 4; ++jt)
                    vf[ks][jt] = *(const bf16x8*)&Vs[ks * 4 + quad][jt * 16 + n16][0];

#pragma unroll
            for (int mt = 0; mt < 2; ++mt) {
                if (mt == 0 && c == 2 * T + 1) continue;   // fully-masked subtile (uniform branch)
                float p[4][4];
#pragma unroll
                for (int reg = 0; reg < 4; ++reg)
#pragma unroll
                    for (int jt = 0; jt < 4; ++jt)
                        p[reg][jt] = __expf(S[mt][jt][reg]);
                if (c == 2 * T + mt) {   // partially-masked diagonal subtile
#pragma unroll
                    for (int reg = 0; reg < 4; ++reg) {
                        const int tr = t0 + (w + mt * 4) * 16 + quad * 4 + reg;
#pragma unroll
                        for (int jt = 0; jt < 4; ++jt)
                            if (c * 64 + jt * 16 + n16 > tr) p[reg][jt] = 0.f;
                    }
                }
#pragma unroll
                for (int reg = 0; reg < 4; ++reg) {
                    lsum[mt][reg] += (p[reg][0] + p[reg][1]) + (p[reg][2] + p[reg][3]);
#pragma unroll
                    for (int jt = 0; jt < 4; ++jt)
                        Ps[w][quad * 4 + reg][jt * 16 + n16] = f2bf(p[reg][jt]);
                }
                bf16x8 pf[2];
#pragma unroll
                for (int ks = 0; ks < 2; ++ks)
                    pf[ks] = *(const bf16x8*)&Ps[w][n16][ks * 32 + quad * 8];
#pragma unroll
                for (int ks = 0; ks < 2; ++ks)
#pragma unroll
                    for (int jt = 0; jt < 4; ++jt)
                        O[mt][jt] = __builtin_amdgcn_mfma_f32_16x16x32_bf16(pf[ks], vf[ks][jt], O[mt][jt], 0, 0, 0);
            }
        }

#pragma unroll
        for (int mt = 0; mt < 2; ++mt)
#pragma unroll
            for (int reg = 0; reg < 4; ++reg) {
                float l = lsum[mt][reg];
#pragma unroll
                for (int off = 1; off < 16; off <<= 1) l += __shfl_xor(l, off, 64);
                const int tr = t0 + (w + mt * 4) * 16 + quad * 4 + reg;
                if (n16 == 0) lb[bh * 2048 + tr] = l;
                const size_t row = (size_t)(b * 2048 + tr) * 1024 + hc;
#pragma unroll
                for (int jt = 0; jt < 4; ++jt)
                    Ob[row + jt * 16 + n16] = f2bf(O[mt][jt][reg]);
            }
    }
}

// ---------------------------------------------------------------------------
// combine flash halves: y = (O0+O1)/(l0+l1); epack = V-image of x[t+1]-y[t].
// ---------------------------------------------------------------------------
__global__ __launch_bounds__(256)
void combine_flash(const u16* __restrict__ Opart, const float* __restrict__ lpart,
                   const u16* __restrict__ xb, u16* __restrict__ y,
                   u16* __restrict__ epack) {
    int i = blockIdx.x * 256 + threadIdx.x;
    int c4 = i & 255, row = i >> 8, t = row & 2047, b = row >> 11;
    int h = c4 >> 4, d0 = (c4 & 15) * 4;
    size_t off = (size_t)row * 1024 + c4 * 4;
    u16x4 o0 = *(const u16x4*)&Opart[off];
    u16x4 o1 = *(const u16x4*)&Opart[(size_t)4096 * 1024 + off];
    int lrow = (b * 16 + h) * 2048 + t;
    float inv = 1.f / (lpart[lrow] + lpart[65536 + lrow]);
    float y0 = (bf2f(o0.x) + bf2f(o1.x)) * inv;
    float y1 = (bf2f(o0.y) + bf2f(o1.y)) * inv;
    float y2 = (bf2f(o0.z) + bf2f(o1.z)) * inv;
    float y3 = (bf2f(o0.w) + bf2f(o1.w)) * inv;
    u16x4 yo;
    yo.x = f2bf(y0); yo.y = f2bf(y1); yo.z = f2bf(y2); yo.w = f2bf(y3);
    *(u16x4*)&y[off] = yo;
    float e0 = 0.f, e1 = 0.f, e2 = 0.f, e3 = 0.f;
    if (t < 2047) {
        u16x4 xv = *(const u16x4*)&xb[off + 1024];
        e0 = bf2f(xv.x) - y0; e1 = bf2f(xv.y) - y1;
        e2 = bf2f(xv.z) - y2; e3 = bf2f(xv.w) - y3;
    }
    size_t base = vimg_idx(b * 16 + h, t, d0);
    epack[base]      = f2bf(e0);
    epack[base + 8]  = f2bf(e1);
    epack[base + 16] = f2bf(e2);
    epack[base + 24] = f2bf(e3);
}

// ---------------------------------------------------------------------------
// ARMA, same 128-row structure, strict mask, no softmax. Static mt unroll.
// ---------------------------------------------------------------------------
__global__ __launch_bounds__(256, 2)
void arma_mfma(const u16* __restrict__ qs, const u16* __restrict__ kapack,
               const u16* __restrict__ epack, u16* __restrict__ Opart) {
    __shared__ __align__(16) u16 Ks[8][64][8];
    __shared__ __align__(16) u16 Es[8][64][8];
    __shared__ __align__(16) u16 Ps[4][16][72];
    const int bh = blockIdx.y, b = bh >> 4, hc = (bh & 15) * 64;
    const int z = blockIdx.z;
    const int tid = threadIdx.x, w = tid >> 6, lane = tid & 63;
    const int n16 = lane & 15, quad = lane >> 4;
    const u16* kbase = kapack + (size_t)bh * 32 * 4096;
    const u16* vbase = epack + (size_t)bh * 32 * 4096;
    u16* Ob = Opart + (size_t)z * 4096 * 1024;

    for (int rep = 0; rep < 2; ++rep) {
        const int T = rep ? 15 - (int)blockIdx.x : (int)blockIdx.x;
        const int t0 = T * 128;
        const int nchunk = 2 * T + 2;

        bf16x8 qf[2][2];
#pragma unroll
        for (int mt = 0; mt < 2; ++mt) {
            const int trow = t0 + (w + mt * 4) * 16 + n16;
            const u16* qp = &qs[(size_t)(b * 2048 + trow) * 1024 + hc + quad * 8];
#pragma unroll
            for (int ks = 0; ks < 2; ++ks) {
                u16x8 qv = *(const u16x8*)(qp + ks * 32);
                u16x8 o;
#pragma unroll
                for (int j = 0; j < 8; ++j) {
                    float zv = bf2f(qv[j]);              // pre-scaled by 1/8
                    o[j] = f2bf(zv < 0.f ? zv : 0.02f * zv);
                }
                qf[mt][ks] = __builtin_bit_cast(bf16x8, o);
            }
        }

        f32x4 O[2][4];
#pragma unroll
        for (int mt = 0; mt < 2; ++mt)
#pragma unroll
            for (int jt = 0; jt < 4; ++jt) O[mt][jt] = f32x4{0.f, 0.f, 0.f, 0.f};

        u16x8 kr0, kr1, vr0, vr1;
        auto pref = [&](int c) {
            const u16* kc = kbase + (size_t)c * 4096;
            const u16* vc = vbase + (size_t)c * 4096;
            kr0 = *(const u16x8*)(kc + tid * 8);
            kr1 = *(const u16x8*)(kc + (256 + tid) * 8);
            vr0 = *(const u16x8*)(vc + tid * 8);
            vr1 = *(const u16x8*)(vc + (256 + tid) * 8);
        };
        if (z < nchunk) pref(z);

        for (int c = z; c < nchunk; c += 2) {
            __syncthreads();
            *(u16x8*)((u16*)Ks + tid * 8)         = kr0;
            *(u16x8*)((u16*)Ks + (256 + tid) * 8) = kr1;
            *(u16x8*)((u16*)Es + tid * 8)         = vr0;
            *(u16x8*)((u16*)Es + (256 + tid) * 8) = vr1;
            __syncthreads();
            if (c + 2 < nchunk) pref(c + 2);

            f32x4 S[2][4];
#pragma unroll
            for (int mt = 0; mt < 2; ++mt)
#pragma unroll
                for (int jt = 0; jt < 4; ++jt) S[mt][jt] = f32x4{0.f, 0.f, 0.f, 0.f};
#pragma unroll
            for (int ks = 0; ks < 2; ++ks)
#pragma unroll
                for (int jt = 0; jt < 4; ++jt) {
                    bf16x8 kf = *(const bf16x8*)&Ks[ks * 4 + quad][jt * 16 + n16][0];
                    S[0][jt] = __builtin_amdgcn_mfma_f32_16x16x32_bf16(qf[0][ks], kf, S[0][jt], 0, 0, 0);
                    S[1][jt] = __builtin_amdgcn_mfma_f32_16x16x32_bf16(qf[1][ks], kf, S[1][jt], 0, 0, 0);
                }
            bf16x8 vf[2][4];
#pragma unroll
            for (int ks = 0; ks < 2; ++ks)
#pragma unroll
                for (int jt = 0; jt < 4; ++jt)
                    vf[ks][jt] = *(const bf16x8*)&Es[ks * 4 + quad][jt * 16 + n16][0];

#pragma unroll
            for (int mt = 0; mt < 2; ++mt) {
                if (mt == 0 && c == 2 * T + 1) continue;   // fully-masked subtile
                if (c == 2 * T + mt) {   // strict mask s < t on diagonal subtile
#pragma unroll
                    for (int reg = 0; reg < 4; ++reg) {
                        const int tr = t0 + (w + mt * 4) * 16 + quad * 4 + reg;
#pragma unroll
                        for (int jt = 0; jt < 4; ++jt)
                            if (c * 64 + jt * 16 + n16 >= tr) S[mt][jt][reg] = 0.f;
                    }
                }
#pragma unroll
                for (int reg = 0; reg < 4; ++reg)
#pragma unroll
                    for (int jt = 0; jt < 4; ++jt)
                        Ps[w][quad * 4 + reg][jt * 16 + n16] = f2bf(S[mt][jt][reg]);
                bf16x8 pf[2];
#pragma unroll
                for (int ks = 0; ks < 2; ++ks)
                    pf[ks] = *(const bf16x8*)&Ps[w][n16][ks * 32 + quad * 8];
#pragma unroll
                for (int ks = 0; ks < 2; ++ks)
#pragma unroll
                    for (int jt = 0; jt < 4; ++jt)
                        O[mt][jt] = __builtin_amdgcn_mfma_f32_16x16x32_bf16(pf[ks], vf[ks][jt], O[mt][jt], 0, 0, 0);
            }
        }

#pragma unroll
        for (int mt = 0; mt < 2; ++mt)
#pragma unroll
            for (int reg = 0; reg < 4; ++reg) {
                const int tr = t0 + (w + mt * 4) * 16 + quad * 4 + reg;
                const size_t row = (size_t)(b * 2048 + tr) * 1024 + hc;
#pragma unroll
                for (int jt = 0; jt < 4; ++jt)
                    Ob[row + jt * 16 + n16] = f2bf(O[mt][jt][reg]);
            }
    }
}

// ---------------------------------------------------------------------------
// combine arma halves: ys = y + O0 + O1 (bf16).
// ---------------------------------------------------------------------------
__global__ __launch_bounds__(256)
void combine_arma(const u16* __restrict__ Opart, const u16* __restrict__ y,
                  u16* __restrict__ ys) {
    int i = blockIdx.x * 256 + threadIdx.x;
    size_t off = (size_t)i * 4;
    u16x4 o0 = *(const u16x4*)&Opart[off];
    u16x4 o1 = *(const u16x4*)&Opart[(size_t)4096 * 1024 + off];
    u16x4 yv = *(const u16x4*)&y[off];
    u16x4 r;
    r.x = f2bf(bf2f(yv.x) + bf2f(o0.x) + bf2f(o1.x));
    r.y = f2bf(bf2f(yv.y) + bf2f(o0.y) + bf2f(o1.y));
    r.z = f2bf(bf2f(yv.z) + bf2f(o0.z) + bf2f(o1.z));
    r.w = f2bf(bf2f(yv.w) + bf2f(o0.w) + bf2f(o1.w));
    *(u16x4*)&ys[off] = r;
}

// ---------------------------------------------------------------------------
extern "C" void kernel_launch(void* const* d_in, const int* in_sizes, int n_in,
                              void* d_out, int out_size, void* d_ws, size_t ws_size,
                              hipStream_t stream) {
    const float* x      = (const float*)d_in[0];
    const float* W_attn = (const float*)d_in[1];
    const float* W_k2   = (const float*)d_in[2];
    const float* W_proj = (const float*)d_in[3];
    float* out = (float*)d_out;

    char* w = (char*)d_ws;
    u16* xb      = (u16*)w; w += (size_t)4096 * 1024 * 2;   //  8 MB (reused as ys)
    u16* Wt_attn = (u16*)w; w += (size_t)2048 * 1024 * 2;   //  4 MB
    u16* Wt_k2   = (u16*)w; w += (size_t)1024 * 1024 * 2;   //  2 MB
    u16* Wt_proj = (u16*)w; w += (size_t)1024 * 1024 * 2;   //  2 MB
    u16* qs      = (u16*)w; w += (size_t)4096 * 1024 * 2;   //  8 MB
    u16* kpack   = (u16*)w; w += (size_t)4096 * 1024 * 2;   //  8 MB
    u16* kapack  = (u16*)w; w += (size_t)4096 * 1024 * 2;   //  8 MB
    u16* xpack   = (u16*)w; w += (size_t)4096 * 1024 * 2;   //  8 MB
    u16* y       = (u16*)w; w += (size_t)4096 * 1024 * 2;   //  8 MB
    u16* epack   = (u16*)w; w += (size_t)4096 * 1024 * 2;   //  8 MB
    u16* Opart   = (u16*)w; w += (size_t)2 * 4096 * 1024 * 2; // 16 MB
    float* lpart = (float*)w; w += (size_t)2 * 65536 * 4;   // 0.5 MB (~80.5 MB)
    u16* ys = xb;   // xb dead after combine_flash

    convert_pack<<<dim3(4096), dim3(256), 0, stream>>>(x, xb, xpack);
    prep_weights<<<dim3(64, 16), dim3(256), 0, stream>>>(W_attn, W_k2, W_proj,
                                                         Wt_attn, Wt_k2, Wt_proj);
    gemm_qk<<<dim3(16, 32), dim3(256), 0, stream>>>(xb, Wt_attn, qs, kpack, 1024);
    gemm64<2><<<dim3(8, 64), dim3(256), 0, stream>>>(xb, Wt_k2, kapack, 1024, 1024);
    flash_mfma<<<dim3(8, 32, 2), dim3(256), 0, stream>>>(qs, kpack, xpack, Opart, lpart);
    combine_flash<<<dim3(4096), dim3(256), 0, stream>>>(Opart, lpart, xb, y, epack);
    arma_mfma<<<dim3(8, 32, 2), dim3(256), 0, stream>>>(qs, kapack, epack, Opart);
    combine_arma<<<dim3(4096), dim3(256), 0, stream>>>(Opart, y, ys);
    gemm64<1><<<dim3(8, 64), dim3(256), 0, stream>>>(ys, Wt_proj, out, 1024, 1024);
}

// Round 9
// 261.115 us; speedup vs baseline: 1.8451x; 1.0794x over previous
//
#include <hip/hip_runtime.h>

// B=2, T=2048, C=1024, H=16, d=64. Inputs/outputs fp32; internal bf16 MFMA.
typedef unsigned short u16;
typedef u16   u16x4  __attribute__((ext_vector_type(4)));
typedef u16   u16x8  __attribute__((ext_vector_type(8)));
typedef __bf16 bf16x8 __attribute__((ext_vector_type(8)));
typedef float  f32x4  __attribute__((ext_vector_type(4)));

__device__ __forceinline__ float bf2f(u16 v) {
    unsigned u = ((unsigned)v) << 16;
    return __builtin_bit_cast(float, u);
}
__device__ __forceinline__ u16 f2bf(float f) {
    unsigned u = __builtin_bit_cast(unsigned, f);
    u += 0x7fffu + ((u >> 16) & 1u);   // RNE
    return (u16)(u >> 16);
}

// Packed operand images: per (bh, 64-s-chunk) a 512-slot x 8-elem tile (4096 u16).
// K-operand image (k=d): slot = (d>>3)*64 + (s&63), elem = d&7
__device__ __forceinline__ size_t kimg_idx(int bh, int s, int d) {
    return ((size_t)(bh * 32 + (s >> 6)) * 4096) + (size_t)(((d >> 3) * 64 + (s & 63)) * 8) + (d & 7);
}
// V-operand image (k=s): slot = ((s&63)>>3)*64 + d, elem = s&7
__device__ __forceinline__ size_t vimg_idx(int bh, int s, int d) {
    return ((size_t)(bh * 32 + (s >> 6)) * 4096) + (size_t)((((s & 63) >> 3) * 64 + d) * 8) + (s & 7);
}

// ---------------------------------------------------------------------------
// fp32 x -> bf16 row-major xb AND V-image xpack.
// ---------------------------------------------------------------------------
__global__ __launch_bounds__(256)
void convert_pack(const float* __restrict__ in, u16* __restrict__ xb,
                  u16* __restrict__ xpack) {
    int i = blockIdx.x * 256 + threadIdx.x;       // [0, 1048576)
    int c4 = i & 255, row = i >> 8;               // row = b*2048 + s
    int s = row & 2047, b = row >> 11;
    float4 v = ((const float4*)in)[i];
    u16x4 o;
    o.x = f2bf(v.x); o.y = f2bf(v.y); o.z = f2bf(v.z); o.w = f2bf(v.w);
    ((u16x4*)xb)[i] = o;
    int h = c4 >> 4, d0 = (c4 & 15) * 4;
    size_t base = vimg_idx(b * 16 + h, s, d0);
    xpack[base]      = o.x;
    xpack[base + 8]  = o.y;
    xpack[base + 16] = o.z;
    xpack[base + 24] = o.w;
}

// ---------------------------------------------------------------------------
// All three weight transposes in one launch. grid (64,16).
// ---------------------------------------------------------------------------
__global__ __launch_bounds__(256)
void prep_weights(const float* __restrict__ Wa, const float* __restrict__ Wk,
                  const float* __restrict__ Wp, u16* __restrict__ Wta,
                  u16* __restrict__ Wtk, u16* __restrict__ Wtp) {
    __shared__ u16 tile[64][65];
    const int bx = blockIdx.x;
    const float* in; u16* out; int Cd, cx;
    if (bx < 32)      { in = Wa; out = Wta; Cd = 2048; cx = bx; }
    else if (bx < 48) { in = Wk; out = Wtk; Cd = 1024; cx = bx - 32; }
    else              { in = Wp; out = Wtp; Cd = 1024; cx = bx - 48; }
    const int c0 = cx * 64, r0 = blockIdx.y * 64;
    const int tid = threadIdx.x;
#pragma unroll
    for (int i = 0; i < 16; ++i) {
        int idx = tid + i * 256;
        int r = idx >> 6, c = idx & 63;
        tile[r][c] = f2bf(in[(size_t)(r0 + r) * Cd + c0 + c]);
    }
    __syncthreads();
#pragma unroll
    for (int i = 0; i < 16; ++i) {
        int idx = tid + i * 256;
        int r = idx >> 6, c = idx & 63;
        out[(size_t)(c0 + r) * 1024 + r0 + c] = tile[c][r];
    }
}

// ---------------------------------------------------------------------------
// Fused GEMM: [4096 x 3072] = xb @ [Wt_attn ; Wt_k2]^T (Bt rows contiguous).
// 128x128 tile, XOR bank swizzle (store row ^ c8*2, read row ^ q*2 — kills
// the 4-way staging-write conflict), 3 blocks/CU (grid 24x32).
// Epilogue: n<1024 -> qs*0.125; n<2048 -> kpack; else sigmoid -> kapack.
// ---------------------------------------------------------------------------
__global__ __launch_bounds__(256, 3)
void gemm_fused(const u16* __restrict__ A, const u16* __restrict__ Bt,
                u16* __restrict__ qs, u16* __restrict__ kpack,
                u16* __restrict__ kapack) {
    const int K = 1024;
    __shared__ __align__(16) u16 As[4][128][8];
    __shared__ __align__(16) u16 Bs[4][128][8];
    const int tid = threadIdx.x;
    const int wave = tid >> 6, lane = tid & 63;
    const int m0 = blockIdx.y * 128, n0 = blockIdx.x * 128;
    const int wm = (wave >> 1) * 64, wn = (wave & 1) * 64;
    const int q = lane >> 4, mr = lane & 15;
    const int sr = tid >> 2, c8 = tid & 3;
    const int sw = c8 * 2;                        // write swizzle
    const int rs = q * 2;                         // read swizzle
    const u16* Ap = A + (size_t)(m0 + sr) * K + c8 * 8;
    const u16* Bp = Bt + (size_t)(n0 + sr) * K + c8 * 8;

    f32x4 acc[4][4];
#pragma unroll
    for (int i = 0; i < 4; ++i)
#pragma unroll
        for (int j = 0; j < 4; ++j) acc[i][j] = f32x4{0.f, 0.f, 0.f, 0.f};

    u16x8 a0, a1, b0, b1;
    auto gload = [&](int k0) {
        a0 = *(const u16x8*)(Ap + k0);
        a1 = *(const u16x8*)(Ap + k0 + (size_t)64 * K);
        b0 = *(const u16x8*)(Bp + k0);
        b1 = *(const u16x8*)(Bp + k0 + (size_t)64 * K);
    };
    gload(0);
    for (int k0 = 0; k0 < K; k0 += 32) {
        __syncthreads();
        *(u16x8*)&As[c8][sr ^ sw][0]        = a0;
        *(u16x8*)&As[c8][(sr + 64) ^ sw][0] = a1;
        *(u16x8*)&Bs[c8][sr ^ sw][0]        = b0;
        *(u16x8*)&Bs[c8][(sr + 64) ^ sw][0] = b1;
        __syncthreads();
        if (k0 + 32 < K) gload(k0 + 32);
        bf16x8 af[4], bfr[4];
#pragma unroll
        for (int i = 0; i < 4; ++i) af[i]  = *(const bf16x8*)&As[q][(wm + i * 16 + mr) ^ rs][0];
#pragma unroll
        for (int j = 0; j < 4; ++j) bfr[j] = *(const bf16x8*)&Bs[q][(wn + j * 16 + mr) ^ rs][0];
#pragma unroll
        for (int i = 0; i < 4; ++i)
#pragma unroll
            for (int j = 0; j < 4; ++j)
                acc[i][j] = __builtin_amdgcn_mfma_f32_16x16x32_bf16(af[i], bfr[j], acc[i][j], 0, 0, 0);
    }
#pragma unroll
    for (int i = 0; i < 4; ++i)
#pragma unroll
        for (int j = 0; j < 4; ++j)
#pragma unroll
            for (int r = 0; r < 4; ++r) {
                int m = m0 + wm + i * 16 + q * 4 + r;
                int n = n0 + wn + j * 16 + mr;
                float v = acc[i][j][r];
                int b = m >> 11, s = m & 2047;
                if (n < 1024) {
                    qs[(size_t)m * 1024 + n] = f2bf(v * 0.125f);
                } else if (n < 2048) {
                    int nn = n - 1024;
                    kpack[kimg_idx(b * 16 + (nn >> 6), s, nn & 63)] = f2bf(v);
                } else {
                    int nn = n - 2048;
                    kapack[kimg_idx(b * 16 + (nn >> 6), s, nn & 63)] =
                        f2bf(1.f / (1.f + __expf(-0.0025f * v)));
                }
            }
}

// ---------------------------------------------------------------------------
// 64x128-tile GEMM (proj): fp32 row-major out. XOR bank swizzle.
// ---------------------------------------------------------------------------
__global__ __launch_bounds__(256, 2)
void gemm64(const u16* __restrict__ A, const u16* __restrict__ Bt,
            float* __restrict__ Cv, int N, int K) {
    __shared__ __align__(16) u16 As[4][64][8];
    __shared__ __align__(16) u16 Bs[4][128][8];
    const int tid = threadIdx.x;
    const int wave = tid >> 6, lane = tid & 63;
    const int m0 = blockIdx.y * 64, n0 = blockIdx.x * 128;
    const int wn0 = wave * 32;
    const int q = lane >> 4, mr = lane & 15;
    const int sr = tid >> 2, c8 = tid & 3;
    const int sw = c8 * 2, rs = q * 2;
    const u16* Ap = A + (size_t)(m0 + sr) * K + c8 * 8;
    const u16* Bp = Bt + (size_t)(n0 + sr) * K + c8 * 8;

    f32x4 acc[4][2];
#pragma unroll
    for (int i = 0; i < 4; ++i)
#pragma unroll
        for (int j = 0; j < 2; ++j) acc[i][j] = f32x4{0.f, 0.f, 0.f, 0.f};

    u16x8 a0, b0, b1;
    auto gload = [&](int k0) {
        a0 = *(const u16x8*)(Ap + k0);
        b0 = *(const u16x8*)(Bp + k0);
        b1 = *(const u16x8*)(Bp + k0 + (size_t)64 * K);
    };
    gload(0);
    for (int k0 = 0; k0 < K; k0 += 32) {
        __syncthreads();
        if (sr < 64) *(u16x8*)&As[c8][sr ^ sw][0] = a0;
        else         *(u16x8*)&As[c8][(sr - 64) ^ sw][0] = a0;   // unreachable (sr<64 always)
        *(u16x8*)&Bs[c8][sr ^ sw][0]        = b0;
        *(u16x8*)&Bs[c8][(sr + 64) ^ sw][0] = b1;
        __syncthreads();
        if (k0 + 32 < K) gload(k0 + 32);
        bf16x8 af[4], bfr[2];
#pragma unroll
        for (int i = 0; i < 4; ++i) af[i]  = *(const bf16x8*)&As[q][(i * 16 + mr) ^ rs][0];
#pragma unroll
        for (int j = 0; j < 2; ++j) bfr[j] = *(const bf16x8*)&Bs[q][(wn0 + j * 16 + mr) ^ rs][0];
#pragma unroll
        for (int i = 0; i < 4; ++i)
#pragma unroll
            for (int j = 0; j < 2; ++j)
                acc[i][j] = __builtin_amdgcn_mfma_f32_16x16x32_bf16(af[i], bfr[j], acc[i][j], 0, 0, 0);
    }
#pragma unroll
    for (int i = 0; i < 4; ++i)
#pragma unroll
        for (int j = 0; j < 2; ++j)
#pragma unroll
            for (int r = 0; r < 4; ++r) {
                int m = m0 + i * 16 + q * 4 + r;
                int n = n0 + wn0 + j * 16 + mr;
                Cv[(size_t)m * N + n] = acc[i][j][r];
            }
}

// ---------------------------------------------------------------------------
// Flash attention: 128-row t-tiles (2 m-tiles/wave: {w, w+4}), s-split (z =
// chunk parity). Block bx handles tile pair {bx, 15-bx}. Static mt unroll
// (dynamic bounds caused scratch demotion in R7).
// ---------------------------------------------------------------------------
__global__ __launch_bounds__(256, 2)
void flash_mfma(const u16* __restrict__ qs, const u16* __restrict__ kpack,
                const u16* __restrict__ xpack, u16* __restrict__ Opart,
                float* __restrict__ lpart) {
    __shared__ __align__(16) u16 Ks[8][64][8];
    __shared__ __align__(16) u16 Vs[8][64][8];
    __shared__ __align__(16) u16 Ps[4][16][72];
    const int bh = blockIdx.y, b = bh >> 4, hc = (bh & 15) * 64;
    const int z = blockIdx.z;
    const int tid = threadIdx.x, w = tid >> 6, lane = tid & 63;
    const int n16 = lane & 15, quad = lane >> 4;
    const u16* kbase = kpack + (size_t)bh * 32 * 4096;
    const u16* vbase = xpack + (size_t)bh * 32 * 4096;
    u16* Ob = Opart + (size_t)z * 4096 * 1024;
    float* lb = lpart + z * 65536;

    for (int rep = 0; rep < 2; ++rep) {
        const int T = rep ? 15 - (int)blockIdx.x : (int)blockIdx.x;
        const int t0 = T * 128;
        const int nchunk = 2 * T + 2;

        bf16x8 qf[2][2];
#pragma unroll
        for (int mt = 0; mt < 2; ++mt) {
            const int trow = t0 + (w + mt * 4) * 16 + n16;
            const u16* qp = &qs[(size_t)(b * 2048 + trow) * 1024 + hc + quad * 8];
            qf[mt][0] = *(const bf16x8*)qp;
            qf[mt][1] = *(const bf16x8*)(qp + 32);
        }

        f32x4 O[2][4];
        float lsum[2][4];
#pragma unroll
        for (int mt = 0; mt < 2; ++mt)
#pragma unroll
            for (int jt = 0; jt < 4; ++jt) { O[mt][jt] = f32x4{0.f, 0.f, 0.f, 0.f}; }
#pragma unroll
        for (int mt = 0; mt < 2; ++mt)
#pragma unroll
            for (int r = 0; r < 4; ++r) lsum[mt][r] = 0.f;

        u16x8 kr0, kr1, vr0, vr1;
        auto pref = [&](int c) {
            const u16* kc = kbase + (size_t)c * 4096;
            const u16* vc = vbase + (size_t)c * 4096;
            kr0 = *(const u16x8*)(kc + tid * 8);
            kr1 = *(const u16x8*)(kc + (256 + tid) * 8);
            vr0 = *(const u16x8*)(vc + tid * 8);
            vr1 = *(const u16x8*)(vc + (256 + tid) * 8);
        };
        if (z < nchunk) pref(z);

        for (int c = z; c < nchunk; c += 2) {
            __syncthreads();
            *(u16x8*)((u16*)Ks + tid * 8)         = kr0;
            *(u16x8*)((u16*)Ks + (256 + tid) * 8) = kr1;
            *(u16x8*)((u16*)Vs + tid * 8)         = vr0;
            *(u16x8*)((u16*)Vs + (256 + tid) * 8) = vr1;
            __syncthreads();
            if (c + 2 < nchunk) pref(c + 2);

            f32x4 S[2][4];
#pragma unroll
            for (int mt = 0; mt < 2; ++mt)
#pragma unroll
                for (int jt = 0; jt < 4; ++jt) S[mt][jt] = f32x4{0.f, 0.f, 0.f, 0.f};
#pragma unroll
            for (int ks = 0; ks < 2; ++ks)
#pragma unroll
                for (int jt = 0; jt < 4; ++jt) {
                    bf16x8 kf = *(const bf16x8*)&Ks[ks * 4 + quad][jt * 16 + n16][0];
                    S[0][jt] = __builtin_amdgcn_mfma_f32_16x16x32_bf16(qf[0][ks], kf, S[0][jt], 0, 0, 0);
                    S[1][jt] = __builtin_amdgcn_mfma_f32_16x16x32_bf16(qf[1][ks], kf, S[1][jt], 0, 0, 0);
                }
            bf16x8 vf[2][4];
#pragma unroll
            for (int ks = 0; ks < 2; ++ks)
#pragma unroll
                for (int jt = 0; jt < 4; ++jt)
                    vf[ks][jt] = *(const bf16x8*)&Vs[ks * 4 + quad][jt * 16 + n16][0];

#pragma unroll
            for (int mt = 0; mt < 2; ++mt) {
                if (mt == 0 && c == 2 * T + 1) continue;   // fully-masked subtile
                float p[4][4];
#pragma unroll
                for (int reg = 0; reg < 4; ++reg)
#pragma unroll
                    for (int jt = 0; jt < 4; ++jt)
                        p[reg][jt] = __expf(S[mt][jt][reg]);
                if (c == 2 * T + mt) {   // partially-masked diagonal subtile
#pragma unroll
                    for (int reg = 0; reg < 4; ++reg) {
                        const int tr = t0 + (w + mt * 4) * 16 + quad * 4 + reg;
#pragma unroll
                        for (int jt = 0; jt < 4; ++jt)
                            if (c * 64 + jt * 16 + n16 > tr) p[reg][jt] = 0.f;
                    }
                }
#pragma unroll
                for (int reg = 0; reg < 4; ++reg) {
                    lsum[mt][reg] += (p[reg][0] + p[reg][1]) + (p[reg][2] + p[reg][3]);
#pragma unroll
                    for (int jt = 0; jt < 4; ++jt)
                        Ps[w][quad * 4 + reg][jt * 16 + n16] = f2bf(p[reg][jt]);
                }
                bf16x8 pf[2];
#pragma unroll
                for (int ks = 0; ks < 2; ++ks)
                    pf[ks] = *(const bf16x8*)&Ps[w][n16][ks * 32 + quad * 8];
#pragma unroll
                for (int ks = 0; ks < 2; ++ks)
#pragma unroll
                    for (int jt = 0; jt < 4; ++jt)
                        O[mt][jt] = __builtin_amdgcn_mfma_f32_16x16x32_bf16(pf[ks], vf[ks][jt], O[mt][jt], 0, 0, 0);
            }
        }

#pragma unroll
        for (int mt = 0; mt < 2; ++mt)
#pragma unroll
            for (int reg = 0; reg < 4; ++reg) {
                float l = lsum[mt][reg];
#pragma unroll
                for (int off = 1; off < 16; off <<= 1) l += __shfl_xor(l, off, 64);
                const int tr = t0 + (w + mt * 4) * 16 + quad * 4 + reg;
                if (n16 == 0) lb[bh * 2048 + tr] = l;
                const size_t row = (size_t)(b * 2048 + tr) * 1024 + hc;
#pragma unroll
                for (int jt = 0; jt < 4; ++jt)
                    Ob[row + jt * 16 + n16] = f2bf(O[mt][jt][reg]);
            }
    }
}

// ---------------------------------------------------------------------------
// combine flash halves: y = (O0+O1)/(l0+l1); epack = V-image of x[t+1]-y[t].
// ---------------------------------------------------------------------------
__global__ __launch_bounds__(256)
void combine_flash(const u16* __restrict__ Opart, const float* __restrict__ lpart,
                   const u16* __restrict__ xb, u16* __restrict__ y,
                   u16* __restrict__ epack) {
    int i = blockIdx.x * 256 + threadIdx.x;
    int c4 = i & 255, row = i >> 8, t = row & 2047, b = row >> 11;
    int h = c4 >> 4, d0 = (c4 & 15) * 4;
    size_t off = (size_t)row * 1024 + c4 * 4;
    u16x4 o0 = *(const u16x4*)&Opart[off];
    u16x4 o1 = *(const u16x4*)&Opart[(size_t)4096 * 1024 + off];
    int lrow = (b * 16 + h) * 2048 + t;
    float inv = 1.f / (lpart[lrow] + lpart[65536 + lrow]);
    float y0 = (bf2f(o0.x) + bf2f(o1.x)) * inv;
    float y1 = (bf2f(o0.y) + bf2f(o1.y)) * inv;
    float y2 = (bf2f(o0.z) + bf2f(o1.z)) * inv;
    float y3 = (bf2f(o0.w) + bf2f(o1.w)) * inv;
    u16x4 yo;
    yo.x = f2bf(y0); yo.y = f2bf(y1); yo.z = f2bf(y2); yo.w = f2bf(y3);
    *(u16x4*)&y[off] = yo;
    float e0 = 0.f, e1 = 0.f, e2 = 0.f, e3 = 0.f;
    if (t < 2047) {
        u16x4 xv = *(const u16x4*)&xb[off + 1024];
        e0 = bf2f(xv.x) - y0; e1 = bf2f(xv.y) - y1;
        e2 = bf2f(xv.z) - y2; e3 = bf2f(xv.w) - y3;
    }
    size_t base = vimg_idx(b * 16 + h, t, d0);
    epack[base]      = f2bf(e0);
    epack[base + 8]  = f2bf(e1);
    epack[base + 16] = f2bf(e2);
    epack[base + 24] = f2bf(e3);
}

// ---------------------------------------------------------------------------
// ARMA, same 128-row structure, strict mask, no softmax. Static mt unroll.
// ---------------------------------------------------------------------------
__global__ __launch_bounds__(256, 2)
void arma_mfma(const u16* __restrict__ qs, const u16* __restrict__ kapack,
               const u16* __restrict__ epack, u16* __restrict__ Opart) {
    __shared__ __align__(16) u16 Ks[8][64][8];
    __shared__ __align__(16) u16 Es[8][64][8];
    __shared__ __align__(16) u16 Ps[4][16][72];
    const int bh = blockIdx.y, b = bh >> 4, hc = (bh & 15) * 64;
    const int z = blockIdx.z;
    const int tid = threadIdx.x, w = tid >> 6, lane = tid & 63;
    const int n16 = lane & 15, quad = lane >> 4;
    const u16* kbase = kapack + (size_t)bh * 32 * 4096;
    const u16* vbase = epack + (size_t)bh * 32 * 4096;
    u16* Ob = Opart + (size_t)z * 4096 * 1024;

    for (int rep = 0; rep < 2; ++rep) {
        const int T = rep ? 15 - (int)blockIdx.x : (int)blockIdx.x;
        const int t0 = T * 128;
        const int nchunk = 2 * T + 2;

        bf16x8 qf[2][2];
#pragma unroll
        for (int mt = 0; mt < 2; ++mt) {
            const int trow = t0 + (w + mt * 4) * 16 + n16;
            const u16* qp = &qs[(size_t)(b * 2048 + trow) * 1024 + hc + quad * 8];
#pragma unroll
            for (int ks = 0; ks < 2; ++ks) {
                u16x8 qv = *(const u16x8*)(qp + ks * 32);
                u16x8 o;
#pragma unroll
                for (int j = 0; j < 8; ++j) {
                    float zv = bf2f(qv[j]);              // pre-scaled by 1/8
                    o[j] = f2bf(zv < 0.f ? zv : 0.02f * zv);
                }
                qf[mt][ks] = __builtin_bit_cast(bf16x8, o);
            }
        }

        f32x4 O[2][4];
#pragma unroll
        for (int mt = 0; mt < 2; ++mt)
#pragma unroll
            for (int jt = 0; jt < 4; ++jt) O[mt][jt] = f32x4{0.f, 0.f, 0.f, 0.f};

        u16x8 kr0, kr1, vr0, vr1;
        auto pref = [&](int c) {
            const u16* kc = kbase + (size_t)c * 4096;
            const u16* vc = vbase + (size_t)c * 4096;
            kr0 = *(const u16x8*)(kc + tid * 8);
            kr1 = *(const u16x8*)(kc + (256 + tid) * 8);
            vr0 = *(const u16x8*)(vc + tid * 8);
            vr1 = *(const u16x8*)(vc + (256 + tid) * 8);
        };
        if (z < nchunk) pref(z);

        for (int c = z; c < nchunk; c += 2) {
            __syncthreads();
            *(u16x8*)((u16*)Ks + tid * 8)         = kr0;
            *(u16x8*)((u16*)Ks + (256 + tid) * 8) = kr1;
            *(u16x8*)((u16*)Es + tid * 8)         = vr0;
            *(u16x8*)((u16*)Es + (256 + tid) * 8) = vr1;
            __syncthreads();
            if (c + 2 < nchunk) pref(c + 2);

            f32x4 S[2][4];
#pragma unroll
            for (int mt = 0; mt < 2; ++mt)
#pragma unroll
                for (int jt = 0; jt < 4; ++jt) S[mt][jt] = f32x4{0.f, 0.f, 0.f, 0.f};
#pragma unroll
            for (int ks = 0; ks < 2; ++ks)
#pragma unroll
                for (int jt = 0; jt < 4; ++jt) {
                    bf16x8 kf = *(const bf16x8*)&Ks[ks * 4 + quad][jt * 16 + n16][0];
                    S[0][jt] = __builtin_amdgcn_mfma_f32_16x16x32_bf16(qf[0][ks], kf, S[0][jt], 0, 0, 0);
                    S[1][jt] = __builtin_amdgcn_mfma_f32_16x16x32_bf16(qf[1][ks], kf, S[1][jt], 0, 0, 0);
                }
            bf16x8 vf[2][4];
#pragma unroll
            for (int ks = 0; ks < 2; ++ks)
#pragma unroll
                for (int jt = 0; jt < 4; ++jt)
                    vf[ks][jt] = *(const bf16x8*)&Es[ks * 4 + quad][jt * 16 + n16][0];

#pragma unroll
            for (int mt = 0; mt < 2; ++mt) {
                if (mt == 0 && c == 2 * T + 1) continue;   // fully-masked subtile
                if (c == 2 * T + mt) {   // strict mask s < t on diagonal subtile
#pragma unroll
                    for (int reg = 0; reg < 4; ++reg) {
                        const int tr = t0 + (w + mt * 4) * 16 + quad * 4 + reg;
#pragma unroll
                        for (int jt = 0; jt < 4; ++jt)
                            if (c * 64 + jt * 16 + n16 >= tr) S[mt][jt][reg] = 0.f;
                    }
                }
#pragma unroll
                for (int reg = 0; reg < 4; ++reg)
#pragma unroll
                    for (int jt = 0; jt < 4; ++jt)
                        Ps[w][quad * 4 + reg][jt * 16 + n16] = f2bf(S[mt][jt][reg]);
                bf16x8 pf[2];
#pragma unroll
                for (int ks = 0; ks < 2; ++ks)
                    pf[ks] = *(const bf16x8*)&Ps[w][n16][ks * 32 + quad * 8];
#pragma unroll
                for (int ks = 0; ks < 2; ++ks)
#pragma unroll
                    for (int jt = 0; jt < 4; ++jt)
                        O[mt][jt] = __builtin_amdgcn_mfma_f32_16x16x32_bf16(pf[ks], vf[ks][jt], O[mt][jt], 0, 0, 0);
            }
        }

#pragma unroll
        for (int mt = 0; mt < 2; ++mt)
#pragma unroll
            for (int reg = 0; reg < 4; ++reg) {
                const int tr = t0 + (w + mt * 4) * 16 + quad * 4 + reg;
                const size_t row = (size_t)(b * 2048 + tr) * 1024 + hc;
#pragma unroll
                for (int jt = 0; jt < 4; ++jt)
                    Ob[row + jt * 16 + n16] = f2bf(O[mt][jt][reg]);
            }
    }
}

// ---------------------------------------------------------------------------
// combine arma halves: ys = y + O0 + O1 (bf16).
// ---------------------------------------------------------------------------
__global__ __launch_bounds__(256)
void combine_arma(const u16* __restrict__ Opart, const u16* __restrict__ y,
                  u16* __restrict__ ys) {
    int i = blockIdx.x * 256 + threadIdx.x;
    size_t off = (size_t)i * 4;
    u16x4 o0 = *(const u16x4*)&Opart[off];
    u16x4 o1 = *(const u16x4*)&Opart[(size_t)4096 * 1024 + off];
    u16x4 yv = *(const u16x4*)&y[off];
    u16x4 r;
    r.x = f2bf(bf2f(yv.x) + bf2f(o0.x) + bf2f(o1.x));
    r.y = f2bf(bf2f(yv.y) + bf2f(o0.y) + bf2f(o1.y));
    r.z = f2bf(bf2f(yv.z) + bf2f(o0.z) + bf2f(o1.z));
    r.w = f2bf(bf2f(yv.w) + bf2f(o0.w) + bf2f(o1.w));
    *(u16x4*)&ys[off] = r;
}

// ---------------------------------------------------------------------------
extern "C" void kernel_launch(void* const* d_in, const int* in_sizes, int n_in,
                              void* d_out, int out_size, void* d_ws, size_t ws_size,
                              hipStream_t stream) {
    const float* x      = (const float*)d_in[0];
    const float* W_attn = (const float*)d_in[1];
    const float* W_k2   = (const float*)d_in[2];
    const float* W_proj = (const float*)d_in[3];
    float* out = (float*)d_out;

    char* w = (char*)d_ws;
    u16* xb      = (u16*)w; w += (size_t)4096 * 1024 * 2;   //  8 MB (reused as ys)
    u16* Wt_attn = (u16*)w; w += (size_t)2048 * 1024 * 2;   //  4 MB ┐ must stay adjacent:
    u16* Wt_k2   = (u16*)w; w += (size_t)1024 * 1024 * 2;   //  2 MB ┘ fused GEMM reads [3072][1024]
    u16* Wt_proj = (u16*)w; w += (size_t)1024 * 1024 * 2;   //  2 MB
    u16* qs      = (u16*)w; w += (size_t)4096 * 1024 * 2;   //  8 MB
    u16* kpack   = (u16*)w; w += (size_t)4096 * 1024 * 2;   //  8 MB
    u16* kapack  = (u16*)w; w += (size_t)4096 * 1024 * 2;   //  8 MB
    u16* xpack   = (u16*)w; w += (size_t)4096 * 1024 * 2;   //  8 MB
    u16* y       = (u16*)w; w += (size_t)4096 * 1024 * 2;   //  8 MB
    u16* epack   = (u16*)w; w += (size_t)4096 * 1024 * 2;   //  8 MB
    u16* Opart   = (u16*)w; w += (size_t)2 * 4096 * 1024 * 2; // 16 MB
    float* lpart = (float*)w; w += (size_t)2 * 65536 * 4;   // 0.5 MB (~80.5 MB)
    u16* ys = xb;   // xb dead after combine_flash

    convert_pack<<<dim3(4096), dim3(256), 0, stream>>>(x, xb, xpack);
    prep_weights<<<dim3(64, 16), dim3(256), 0, stream>>>(W_attn, W_k2, W_proj,
                                                         Wt_attn, Wt_k2, Wt_proj);
    gemm_fused<<<dim3(24, 32), dim3(256), 0, stream>>>(xb, Wt_attn, qs, kpack, kapack);
    flash_mfma<<<dim3(8, 32, 2), dim3(256), 0, stream>>>(qs, kpack, xpack, Opart, lpart);
    combine_flash<<<dim3(4096), dim3(256), 0, stream>>>(Opart, lpart, xb, y, epack);
    arma_mfma<<<dim3(8, 32, 2), dim3(256), 0, stream>>>(qs, kapack, epack, Opart);
    combine_arma<<<dim3(4096), dim3(256), 0, stream>>>(Opart, y, ys);
    gemm64<<<dim3(8, 64), dim3(256), 0, stream>>>(ys, Wt_proj, out, 1024, 1024);
}